// Round 9
// baseline (212.681 us; speedup 1.0000x reference)
//
#include <hip/hip_runtime.h>
#include <stdint.h>

// Problem constants
#define EMB   1024
#define HEADS 16
#define HD    64
#define BB    2
#define TT    2048
#define MTOT  (BB*TT)
#define LDP   72               // padded LDS stride for proj GEMM tiles

#define ELX (4194304u)         // MTOT*EMB elems
#define ELW (1048576u)         // EMB*EMB elems

#define CSCALE (0.125f * 1.44269504088896f)   // HD^-0.5 * log2(e)

typedef __attribute__((ext_vector_type(8))) short short8;
typedef __attribute__((ext_vector_type(4))) float f32x4;
typedef __attribute__((ext_vector_type(4))) unsigned short us4;

__device__ __forceinline__ float bf2f(ushort u) {
  union { uint32_t u; float f; } x; x.u = ((uint32_t)u) << 16; return x.f;
}
__device__ __forceinline__ ushort f2bf(float f) {
  union { float f; uint32_t u; } x; x.f = f;
  uint32_t u = x.u;
  u += 0x7fffu + ((u >> 16) & 1u);   // RNE
  return (ushort)(u >> 16);
}
__device__ __forceinline__ uint32_t pack2(uint32_t lo, uint32_t hi) {
  return (lo >> 16) | (hi & 0xFFFF0000u);   // [bf16(lo), bf16(hi)] truncation
}
__device__ __forceinline__ short8 pack8(f32x4 a, f32x4 b) {
  union { f32x4 v; uint32_t u[4]; } A, B;
  A.v = a; B.v = b;
  union { uint32_t d[4]; short8 s; } R;
  R.d[0] = pack2(A.u[0], A.u[1]);
  R.d[1] = pack2(A.u[2], A.u[3]);
  R.d[2] = pack2(B.u[0], B.u[1]);
  R.d[3] = pack2(B.u[2], B.u[3]);
  return R.s;
}
__device__ __forceinline__ short8 cvt8_rne(const float* f) {
  f32x4 a = *(const f32x4*)f;
  f32x4 b = *(const f32x4*)(f + 4);
  short8 r;
  r[0] = (short)f2bf(a[0]); r[1] = (short)f2bf(a[1]);
  r[2] = (short)f2bf(a[2]); r[3] = (short)f2bf(a[3]);
  r[4] = (short)f2bf(b[0]); r[5] = (short)f2bf(b[1]);
  r[6] = (short)f2bf(b[2]); r[7] = (short)f2bf(b[3]);
  return r;
}

// async global->LDS, 16B per lane; lds dest must be wave-uniform base
__device__ __forceinline__ void gll16(const void* g, void* l) {
  __builtin_amdgcn_global_load_lds((const __attribute__((address_space(1))) void*)g,
                                   (__attribute__((address_space(3))) void*)l,
                                   16, 0, 0);
}

// ---------------------------------------------------------------------------
// dtype probe (parallel): 1 = bf16 storage, 0 = fp32 storage
// ---------------------------------------------------------------------------
__global__ void detect_dtype(const uint32_t* __restrict__ x, int* __restrict__ flag) {
  const int lane = threadIdx.x & 63;
  int cnt = 0;
#pragma unroll
  for (int i = 0; i < 4; ++i) {
    const uint32_t v = x[lane * 4 + i];
    const uint32_t e = ((v & 0xFFFFu) >> 7) & 0xFFu;
    cnt += (e >= 0x70u && e <= 0x8Fu) ? 1 : 0;
  }
#pragma unroll
  for (int off = 1; off < 64; off <<= 1) cnt += __shfl_xor(cnt, off);
  if (lane == 0) *flag = (cnt > 128) ? 1 : 0;
}

// convert Wq,Wk,Wv -> contiguous bf16 w3[3*ELW] AND x -> xb[ELX] (RNE).
// grid 3584 x 256: first 1536 blocks = weights, last 2048 = x (block-aligned:
// 1536*2048 == 3*ELW, so the branch is uniform per block).
__global__ __launch_bounds__(256) void convert4(const void* __restrict__ w0,
                                                const void* __restrict__ w1,
                                                const void* __restrict__ w2,
                                                const void* __restrict__ x,
                                                ushort* __restrict__ w3,
                                                ushort* __restrict__ xb,
                                                const int* __restrict__ flag) {
  const size_t i = ((size_t)blockIdx.x * 256 + threadIdx.x) * 8;
  const int isbf = *flag;
  if (i < 3u * ELW) {
    const int wi = (int)(i >> 20);
    const size_t off = i & (ELW - 1);
    const void* src = (wi == 0) ? w0 : (wi == 1) ? w1 : w2;
    if (isbf) *(short8*)(w3 + i) = *(const short8*)((const ushort*)src + off);
    else      *(short8*)(w3 + i) = cvt8_rne((const float*)src + off);
  } else {
    const size_t j = i - 3u * ELW;           // 0..ELX-1
    if (isbf) *(short8*)(xb + j) = *(const short8*)((const ushort*)x + j);
    else      *(short8*)(xb + j) = cvt8_rne((const float*)x + j);
  }
}

// ---------------------------------------------------------------------------
// QKV GEMM, all-bf16 both-operand gll16, issue-early/drain-late:
//   tile 256m x 192n, BK=64, 8 waves (2x4), acc[8][3], 16 K-tiles,
//   ONE barrier per K-tile. Staging for K-tile t+1 (7 gll/thread) issues at
//   the START of K-tile t's compute so the barrier's vmcnt(0) drain is
//   covered by the 48 MFMA + 22 ds_reads of the compute phase.
// N=3072 merges Q/K/V (w3 contiguous); epilogue routes by mat = n>>10.
// LDS double-buffered 112 KB; XOR chunk swizzle (slot = chunk ^ (row&7)),
// applied via pre-swizzled gll SOURCE + swizzled read (both-sides, rule #21).
// Grid 256 = 1 block/CU. XCD k owns mt-pair {2k,2k+1}: its 512 xb rows
// (1 MB bf16) stay L2-resident; x read from L3/HBM exactly once.
// ---------------------------------------------------------------------------
#define ASZ (256 * 64)   // elems per A buffer
#define BSZ (192 * 64)   // elems per B buffer

__device__ __forceinline__ void qkv_core(const ushort* __restrict__ xb,
                                         const ushort* __restrict__ W,
                                         int m0, int n0r,
                                         ushort* As0, ushort* Bs0,
                                         f32x4 acc[8][3]) {
  const int tid  = threadIdx.x;
  const int w    = tid >> 6;
  const int lane = tid & 63;
  const int quad = lane >> 4;
  const int l16  = lane & 15;
  const int wr   = w >> 2, wc = w & 3;

  const int prow = tid >> 3;                 // row within 64-row issue group
  const int c    = tid & 7;                  // physical 16B slot within row
  const int sw   = c ^ (prow & 7);           // logical chunk staged at slot c
  const int rsw  = l16 & 7;                  // read-side swizzle key

  // --- staging helpers (both gll, source pre-swizzled, LDS linear) --------
  auto stageB = [&](int cur, int kt) {
#pragma unroll
    for (int g = 0; g < 3; ++g)
      gll16(W + (size_t)(n0r + g * 64 + prow) * EMB + kt * 64 + sw * 8,
            Bs0 + cur * BSZ + g * 4096 + w * 512);
  };
  auto stageA = [&](int cur, int kt) {
#pragma unroll
    for (int g = 0; g < 4; ++g)
      gll16(xb + (size_t)(m0 + g * 64 + prow) * EMB + kt * 64 + sw * 8,
            As0 + cur * ASZ + g * 4096 + w * 512);
  };

  // --- prologue: stage K-tile 0 into buf 0 --------------------------------
  stageB(0, 0);
  stageA(0, 0);
  __syncthreads();

  // --- main loop: compute buf[cur], stage t+1 into buf[cur^1] -------------
  for (int t = 0; t < 16; ++t) {
    const int cur = t & 1, nxt = cur ^ 1;
    if (t < 15) {                            // issue-early (cover the drain)
      stageB(nxt, t + 1);
      stageA(nxt, t + 1);
    }

    const ushort* Ab = As0 + cur * ASZ;
    const ushort* Bb = Bs0 + cur * BSZ;
    short8 bf_[3][2];
#pragma unroll
    for (int ni = 0; ni < 3; ++ni)
#pragma unroll
      for (int ks = 0; ks < 2; ++ks)
        bf_[ni][ks] = *(const short8*)&Bb[(wc * 48 + ni * 16 + l16) * 64 +
                                          ((ks * 4 + quad) ^ rsw) * 8];
#pragma unroll
    for (int mi = 0; mi < 8; ++mi) {
      const int arow = (wr * 128 + mi * 16 + l16) * 64;
      short8 a0 = *(const short8*)&Ab[arow + ((quad) ^ rsw) * 8];
      short8 a1 = *(const short8*)&Ab[arow + ((4 + quad) ^ rsw) * 8];
#pragma unroll
      for (int ni = 0; ni < 3; ++ni) {
        acc[mi][ni] = __builtin_amdgcn_mfma_f32_16x16x32_bf16(a0, bf_[ni][0], acc[mi][ni], 0, 0, 0);
        acc[mi][ni] = __builtin_amdgcn_mfma_f32_16x16x32_bf16(a1, bf_[ni][1], acc[mi][ni], 0, 0, 0);
      }
    }
    __syncthreads();                         // single drain point per K-tile
  }
}

__global__ __launch_bounds__(512, 2) void qkv_pipe(const ushort* __restrict__ xb,
                                                   const ushort* __restrict__ w3,
                                                   const void* __restrict__ bq,
                                                   const void* __restrict__ bk,
                                                   const void* __restrict__ bv,
                                                   ushort* __restrict__ qo,
                                                   ushort* __restrict__ ko,
                                                   ushort* __restrict__ vo,
                                                   const int* __restrict__ flag) {
  __shared__ __align__(16) ushort As2[2 * ASZ];   // 64 KB
  __shared__ __align__(16) ushort Bs2[2 * BSZ];   // 48 KB
  const int bid = blockIdx.x;              // 256 blocks, 1/CU
  const int xcd = bid & 7;                 // HW round-robin: bid%8 = XCD
  const int mt  = xcd * 2 + ((bid >> 3) & 1);  // XCD k owns mt {2k,2k+1}
  const int nt  = bid >> 4;                // 0..15: W panels stream through
  const int m0  = mt * 256;
  const int n0r = nt * 192;

  f32x4 acc[8][3];
#pragma unroll
  for (int a = 0; a < 8; ++a)
#pragma unroll
    for (int b = 0; b < 3; ++b) acc[a][b] = (f32x4){0.f, 0.f, 0.f, 0.f};

  qkv_core(xb, w3, m0, n0r, As2, Bs2, acc);

  const int isbf = *flag;
  const int tid  = threadIdx.x;
  const int w    = tid >> 6;
  const int lane = tid & 63;
  const int quad = lane >> 4;
  const int l16  = lane & 15;
  const int wr   = w >> 2, wc = w & 3;

#pragma unroll
  for (int ni = 0; ni < 3; ++ni) {
    const int n   = n0r + wc * 48 + ni * 16 + l16;   // 0..3071
    const int mat = n >> 10, nn = n & 1023;          // uniform per fragment
    const void* bias = (mat == 0) ? bq : (mat == 1) ? bk : bv;
    const float bv_ = isbf ? bf2f(((const ushort*)bias)[nn]) : ((const float*)bias)[nn];
    const int h = nn >> 6, d = nn & 63;
    const float sc = (mat == 0) ? CSCALE : 1.0f;
    ushort* dqk = (mat == 0) ? qo : ko;
#pragma unroll
    for (int mi = 0; mi < 8; ++mi) {
      const int m = m0 + wr * 128 + mi * 16 + quad * 4;
      const int b = m >> 11, tt = m & (TT - 1);
      if (mat == 2) {
        us4 pk;
#pragma unroll
        for (int r = 0; r < 4; ++r) pk[r] = f2bf(acc[mi][ni][r] + bv_);
        *(us4*)&vo[((size_t)((b * HEADS + h) * HD + d)) * TT + tt] = pk;
      } else {
#pragma unroll
        for (int r = 0; r < 4; ++r)
          dqk[((size_t)((b * HEADS + h) * TT + tt + r)) * HD + d] =
              f2bf((acc[mi][ni][r] + bv_) * sc);
      }
    }
  }
}

// ---------------------------------------------------------------------------
// Causal flash attention with S^T trick (QK MFMA computes S^T: A=K, B=Q).
// r9: K/V staging moved to gll16 double-buffer with issue-early/drain-late
// (the qkv-proven schedule): per K-tile, stage(buf^1, kt+1) issues FIRST,
// compute runs on buf, then ONE barrier. Removes one barrier/tile, all
// staging ds_writes, and the named global->reg prefetch (-32 VGPR); the
// gll loads get the whole compute phase (~600 cyc) to land instead of a
// cold vmcnt(0) drain. Swizzle: pre-swizzled gll SOURCE + swizzled read
// (both-sides, rule #21) — read side identical to r8 (0-conflict idiom).
// ---------------------------------------------------------------------------
__global__ __launch_bounds__(256) void attn3(const ushort* __restrict__ qw,
                                             const ushort* __restrict__ kw,
                                             const ushort* __restrict__ vtw,
                                             ushort* __restrict__ out) {
  __shared__ __align__(16) ushort Ks[2][64 * 64];    // 16 KB
  __shared__ __align__(16) ushort Vts[2][64 * 64];   // 16 KB
  __shared__ __align__(16) ushort Ps[4][16 * 64];    // 8 KB (2 KB/wave)

  const int bid = blockIdx.x;
  const int j  = bid >> 8;
  const int r8 = bid & 255;
  const int qh = r8 & 31;
  const int bh = j * 8 + (r8 >> 5);
  int qt;
  if      (j == 0) qt = qh;
  else if (j == 1) qt = 31 - qh;
  else if (j == 2) qt = (qh + 16) & 31;
  else             qt = 31 - ((qh + 16) & 31);
  const int h = bh & (HEADS - 1);
  const int b = bh >> 4;

  const int tid  = threadIdx.x;
  const int w    = tid >> 6;
  const int lane = tid & 63;
  const int quad = lane >> 4;
  const int l16  = lane & 15;
  const int rsw  = l16 & 7;          // read-side swizzle key (fragment row&7)

  const size_t hoff = ((size_t)(b * HEADS + h)) * TT * HD;
  const ushort* Qg = qw + hoff;
  const ushort* Kg = kw + hoff;
  const ushort* Vg = vtw + hoff;     // [d][T]
  const int q0 = qt * 64;

  short8 qf[2];
  {
    const ushort* qrow = Qg + (size_t)(q0 + w * 16 + l16) * HD;
    qf[0] = *(const short8*)(qrow + quad * 8);
    qf[1] = *(const short8*)(qrow + 32 + quad * 8);
  }

  // gll staging geometry: issue g covers physical chunks p = g*256 + tid;
  // row = g*32 + (tid>>3), slot = tid&7 holds logical chunk slot^(row&7)
  // -> pre-swizzle the SOURCE chunk, LDS stays linear (rule #21).
  const int prow = tid >> 3;                       // 0..31 (+32 per issue)
  const int sc_  = (tid & 7) ^ (prow & 7);         // pre-swizzled src chunk
  const ushort* Kb = Kg + (size_t)prow * HD + sc_ * 8;  // + (kt*64+g*32)*HD
  const ushort* Vb = Vg + (size_t)prow * TT + sc_ * 8;  // + g*32*TT + kt*64

  auto stage = [&](int buf, int kt) {
#pragma unroll
    for (int g = 0; g < 2; ++g) {
      gll16(Kb + (size_t)(kt * 64 + g * 32) * HD, &Ks[buf][g * 2048 + w * 512]);
      gll16(Vb + (size_t)(g * 32) * TT + kt * 64, &Vts[buf][g * 2048 + w * 512]);
    }
  };

  float lsp[4] = {0.f, 0.f, 0.f, 0.f};   // per-lane partial row sums, q = l16
  f32x4 O[4];
#pragma unroll
  for (int ni = 0; ni < 4; ++ni) O[ni] = (f32x4){0.f, 0.f, 0.f, 0.f};

  auto compute_tile = [&](int kt, int cur) {
    // S^T = K . Q^T : lane(quad,l16) holds keys ni*16+quad*4+r at q-col l16
    f32x4 s[4];
#pragma unroll
    for (int ni = 0; ni < 4; ++ni) s[ni] = (f32x4){0.f, 0.f, 0.f, 0.f};
#pragma unroll
    for (int ks = 0; ks < 2; ++ks) {
#pragma unroll
      for (int ni = 0; ni < 4; ++ni) {
        short8 kb = *(const short8*)&Ks[cur][(ni * 16 + l16) * 64 +
                                            ((ks * 4 + quad) ^ rsw) * 8];
        s[ni] = __builtin_amdgcn_mfma_f32_16x16x32_bf16(kb, qf[ks], s[ni], 0, 0, 0);
      }
    }
    if (kt == qt) {   // diagonal tile: mask key > q (both local to the tile)
      const int qq = w * 16 + l16;
#pragma unroll
      for (int ni = 0; ni < 4; ++ni) {
#pragma unroll
        for (int r = 0; r < 4; ++r)
          if (ni * 16 + quad * 4 + r > qq) s[ni][r] = -__builtin_inff();
      }
    }
    // p = 2^s; keys are register-contiguous -> pack pairs + b64 writes.
    // P[q=l16][key col ni*16+quad*4]: logical chunk 2ni+(quad>>1),
    // half (quad&1); physical chunk = logical ^ (l16&7).
#pragma unroll
    for (int ni = 0; ni < 4; ++ni) {
      union { float f; uint32_t u; } p0, p1, p2, p3;
      p0.f = exp2f(s[ni][0]); p1.f = exp2f(s[ni][1]);
      p2.f = exp2f(s[ni][2]); p3.f = exp2f(s[ni][3]);
      lsp[ni] += (p0.f + p1.f) + (p2.f + p3.f);
      uint2 dw;
      dw.x = pack2(p0.u, p1.u);
      dw.y = pack2(p2.u, p3.u);
      const int slot = (2 * ni + (quad >> 1)) ^ rsw;
      *(uint2*)&Ps[w][l16 * 64 + slot * 8 + (quad & 1) * 4] = dw;
    }
    // O += P V  (A = P from wave-private LDS, B = Vt)
#pragma unroll
    for (int ks = 0; ks < 2; ++ks) {
      short8 a = *(const short8*)&Ps[w][l16 * 64 + ((ks * 4 + quad) ^ rsw) * 8];
#pragma unroll
      for (int ni = 0; ni < 4; ++ni) {
        short8 vb = *(const short8*)&Vts[cur][(ni * 16 + l16) * 64 +
                                              ((ks * 4 + quad) ^ rsw) * 8];
        O[ni] = __builtin_amdgcn_mfma_f32_16x16x32_bf16(a, vb, O[ni], 0, 0, 0);
      }
    }
  };

  // prologue: stage tile 0 into buf 0; one barrier per tile thereafter
  stage(0, 0);
  __syncthreads();
  for (int kt = 0; kt <= qt; ++kt) {
    const int cur = kt & 1;
    if (kt < qt) stage(cur ^ 1, kt + 1);   // issue-early (covers the drain)
    compute_tile(kt, cur);
    __syncthreads();                       // drains gll + guards buf reuse
  }

  // reduce ls across quads (each lane then holds total for q = l16)
  float lst = (lsp[0] + lsp[1]) + (lsp[2] + lsp[3]);
  lst += __shfl_xor(lst, 16);
  lst += __shfl_xor(lst, 32);

#pragma unroll
  for (int r = 0; r < 4; ++r) {
    const float inv = 1.0f / __shfl(lst, (lane & 48) | (quad * 4 + r));
    const int t = q0 + w * 16 + quad * 4 + r;
#pragma unroll
    for (int ni = 0; ni < 4; ++ni) {
      out[((size_t)(b * TT + t)) * EMB + h * HD + ni * 16 + l16] = f2bf(O[ni][r] * inv);
    }
  }
}

// ---------------------------------------------------------------------------
// Output projection: 128m x 64n tiles (32 mt x 16 nt = 512 blocks, 2/CU).
// Halves Wo L2 traffic vs tileM=64 (Wo re-read by 32 m-tiles, not 64).
// BK=64, 3-set distance-2 rotation. Wave w owns rows [w*32, w*32+32).
// ---------------------------------------------------------------------------
template<bool WBF>
__device__ __forceinline__ void proj_core(const ushort* __restrict__ A,
                                          const void* __restrict__ Wo,
                                          int m0, int n0,
                                          ushort* As, ushort* Ws,
                                          f32x4 acc[2][4]) {
  const int tid  = threadIdx.x;
  const int w    = tid >> 6;
  const int lane = tid & 63;
  const int quad = lane >> 4;
  const int l16  = lane & 15;
  const int arow = tid >> 1;            // 0..127
  const int acol = (tid & 1) * 32;      // 32 bf16 cols
  const int brow = tid >> 2;            // 0..63
  const int bcol = (tid & 3) * 16;      // 16 cols

  const size_t aoff = (size_t)(m0 + arow) * EMB + acol;
  const size_t boff = (size_t)(n0 + brow) * EMB + bcol;

  short8 ab[3][4];   // A: 32 bf16
  short8 wb[3][2];   // W bf16: 16
  f32x4  wf[3][4];   // W fp32: 16

#pragma unroll
  for (int s = 0; s < 2; ++s) {
#pragma unroll
    for (int i = 0; i < 4; ++i)
      ab[s][i] = *(const short8*)(A + aoff + 64 * s + 8 * i);
    if constexpr (WBF) {
      wb[s][0] = *(const short8*)((const ushort*)Wo + boff + 64 * s);
      wb[s][1] = *(const short8*)((const ushort*)Wo + boff + 64 * s + 8);
    } else {
#pragma unroll
      for (int i = 0; i < 4; ++i)
        wf[s][i] = *(const f32x4*)((const float*)Wo + boff + 64 * s + 4 * i);
    }
  }

#pragma unroll
  for (int it = 0; it < 16; ++it) {
    const int k0 = it * 64;
    const int cur = it % 3, nxt = (it + 2) % 3;
    __syncthreads();
#pragma unroll
    for (int i = 0; i < 4; ++i)
      *(short8*)&As[arow * LDP + acol + 8 * i] = ab[cur][i];
    if constexpr (WBF) {
      *(short8*)&Ws[brow * LDP + bcol]     = wb[cur][0];
      *(short8*)&Ws[brow * LDP + bcol + 8] = wb[cur][1];
    } else {
      *(short8*)&Ws[brow * LDP + bcol]     = pack8(wf[cur][0], wf[cur][1]);
      *(short8*)&Ws[brow * LDP + bcol + 8] = pack8(wf[cur][2], wf[cur][3]);
    }
    if (it + 2 < 16) {
      const int kn = k0 + 128;
#pragma unroll
      for (int i = 0; i < 4; ++i)
        ab[nxt][i] = *(const short8*)(A + aoff + kn + 8 * i);
      if constexpr (WBF) {
        wb[nxt][0] = *(const short8*)((const ushort*)Wo + boff + kn);
        wb[nxt][1] = *(const short8*)((const ushort*)Wo + boff + kn + 8);
      } else {
#pragma unroll
        for (int i = 0; i < 4; ++i)
          wf[nxt][i] = *(const f32x4*)((const float*)Wo + boff + kn + 4 * i);
      }
    }
    __syncthreads();

#pragma unroll
    for (int ks = 0; ks < 2; ++ks) {
      short8 a_[2], b_[4];
#pragma unroll
      for (int i = 0; i < 2; ++i)
        a_[i] = *(const short8*)&As[(w * 32 + i * 16 + l16) * LDP + ks * 32 + quad * 8];
#pragma unroll
      for (int i = 0; i < 4; ++i)
        b_[i] = *(const short8*)&Ws[(i * 16 + l16) * LDP + ks * 32 + quad * 8];
#pragma unroll
      for (int mi = 0; mi < 2; ++mi)
#pragma unroll
        for (int ni = 0; ni < 4; ++ni)
          acc[mi][ni] = __builtin_amdgcn_mfma_f32_16x16x32_bf16(a_[mi], b_[ni], acc[mi][ni], 0, 0, 0);
    }
  }
}

__global__ __launch_bounds__(256) void proj_pipe(const ushort* __restrict__ A,
                                                 const void* __restrict__ Wo,
                                                 const void* __restrict__ bo,
                                                 void* __restrict__ out,
                                                 const int* __restrict__ flag) {
  __shared__ __align__(16) ushort As[128 * LDP];
  __shared__ __align__(16) ushort Ws[64 * LDP];
  const int nt = blockIdx.x & 15;        // consecutive bids -> round-robin XCDs
  const int mt = blockIdx.x >> 4;        // 0..31 (128-row tiles)
  const int n0 = nt * 64;
  const int m0 = mt * 128;

  f32x4 acc[2][4];
#pragma unroll
  for (int i = 0; i < 2; ++i)
#pragma unroll
    for (int jj = 0; jj < 4; ++jj) acc[i][jj] = (f32x4){0.f, 0.f, 0.f, 0.f};

  const int isbf = *flag;
  if (isbf) proj_core<true >(A, Wo, m0, n0, As, Ws, acc);
  else      proj_core<false>(A, Wo, m0, n0, As, Ws, acc);

  const int tid  = threadIdx.x;
  const int w    = tid >> 6;
  const int lane = tid & 63;
  const int quad = lane >> 4;
  const int l16  = lane & 15;

#pragma unroll
  for (int ni = 0; ni < 4; ++ni) {
    const int n = n0 + ni * 16 + l16;
    const float bv_ = isbf ? bf2f(((const ushort*)bo)[n]) : ((const float*)bo)[n];
#pragma unroll
    for (int mi = 0; mi < 2; ++mi) {
#pragma unroll
      for (int r = 0; r < 4; ++r) {
        const int m = m0 + w * 32 + mi * 16 + quad * 4 + r;
        const float v = acc[mi][ni][r] + bv_;
        if (isbf) ((ushort*)out)[(size_t)m * EMB + n] = f2bf(v);
        else      ((float*) out)[(size_t)m * EMB + n] = v;
      }
    }
  }
}

// ---------------------------------------------------------------------------
extern "C" void kernel_launch(void* const* d_in, const int* in_sizes, int n_in,
                              void* d_out, int out_size, void* d_ws, size_t ws_size,
                              hipStream_t stream) {
  const void* x  = d_in[0];
  const void* Wq = d_in[1];
  const void* bq = d_in[2];
  const void* Wk = d_in[3];
  const void* bk = d_in[4];
  const void* Wv = d_in[5];
  const void* bv = d_in[6];
  const void* Wo = d_in[7];
  const void* bo = d_in[8];

  int* flag = (int*)d_ws;
  ushort* base = (ushort*)((char*)d_ws + 256);

  // ws layout (33.56 MB budget):
  //   q:[0,ELX) k:[ELX,2ELX) vt:[2ELX,3ELX)
  //   w3 (3*ELW, dead after qkv) and o (ELX) share [3ELX,4ELX)
  // xb (bf16 copy of x, ELX ushorts) lives in d_out: dead before proj_pipe
  // writes it, and out_size >= ELX*2 for both fp32 and bf16 outputs.
  ushort* q_ws  = base;
  ushort* k_ws  = q_ws + ELX;
  ushort* vt_ws = k_ws + ELX;
  ushort* w3    = vt_ws + ELX;
  ushort* o_ws  = vt_ws + ELX;
  ushort* xb    = (ushort*)d_out;

  detect_dtype<<<dim3(1), dim3(64), 0, stream>>>((const uint32_t*)x, flag);
  convert4<<<dim3(3584), dim3(256), 0, stream>>>(Wq, Wk, Wv, x, w3, xb, flag);
  qkv_pipe<<<dim3(256), dim3(512), 0, stream>>>(xb, w3, bq, bk, bv,
                                                q_ws, k_ws, vt_ws, flag);
  attn3<<<dim3(1024), dim3(256), 0, stream>>>(q_ws, k_ws, vt_ws, o_ws);
  proj_pipe<<<dim3(512), dim3(256), 0, stream>>>(o_ws, Wo, bo, d_out, flag);
}

// Round 10
// 198.527 us; speedup vs baseline: 1.0713x; 1.0713x over previous
//
#include <hip/hip_runtime.h>
#include <stdint.h>

// Problem constants
#define EMB   1024
#define HEADS 16
#define HD    64
#define BB    2
#define TT    2048
#define MTOT  (BB*TT)

#define ELX (4194304u)         // MTOT*EMB elems
#define ELW (1048576u)         // EMB*EMB elems

#define CSCALE (0.125f * 1.44269504088896f)   // HD^-0.5 * log2(e)

typedef __attribute__((ext_vector_type(8))) short short8;
typedef __attribute__((ext_vector_type(4))) float f32x4;
typedef __attribute__((ext_vector_type(4))) unsigned short us4;

__device__ __forceinline__ float bf2f(ushort u) {
  union { uint32_t u; float f; } x; x.u = ((uint32_t)u) << 16; return x.f;
}
__device__ __forceinline__ ushort f2bf(float f) {
  union { float f; uint32_t u; } x; x.f = f;
  uint32_t u = x.u;
  u += 0x7fffu + ((u >> 16) & 1u);   // RNE
  return (ushort)(u >> 16);
}
__device__ __forceinline__ uint32_t pack2(uint32_t lo, uint32_t hi) {
  return (lo >> 16) | (hi & 0xFFFF0000u);   // [bf16(lo), bf16(hi)] truncation
}
__device__ __forceinline__ short8 cvt8_rne(const float* f) {
  f32x4 a = *(const f32x4*)f;
  f32x4 b = *(const f32x4*)(f + 4);
  short8 r;
  r[0] = (short)f2bf(a[0]); r[1] = (short)f2bf(a[1]);
  r[2] = (short)f2bf(a[2]); r[3] = (short)f2bf(a[3]);
  r[4] = (short)f2bf(b[0]); r[5] = (short)f2bf(b[1]);
  r[6] = (short)f2bf(b[2]); r[7] = (short)f2bf(b[3]);
  return r;
}

// async global->LDS, 16B per lane; lds dest must be wave-uniform base
__device__ __forceinline__ void gll16(const void* g, void* l) {
  __builtin_amdgcn_global_load_lds((const __attribute__((address_space(1))) void*)g,
                                   (__attribute__((address_space(3))) void*)l,
                                   16, 0, 0);
}

// ---------------------------------------------------------------------------
// dtype probe (parallel): 1 = bf16 storage, 0 = fp32 storage
// ---------------------------------------------------------------------------
__global__ void detect_dtype(const uint32_t* __restrict__ x, int* __restrict__ flag) {
  const int lane = threadIdx.x & 63;
  int cnt = 0;
#pragma unroll
  for (int i = 0; i < 4; ++i) {
    const uint32_t v = x[lane * 4 + i];
    const uint32_t e = ((v & 0xFFFFu) >> 7) & 0xFFu;
    cnt += (e >= 0x70u && e <= 0x8Fu) ? 1 : 0;
  }
#pragma unroll
  for (int off = 1; off < 64; off <<= 1) cnt += __shfl_xor(cnt, off);
  if (lane == 0) *flag = (cnt > 128) ? 1 : 0;
}

// convert Wq,Wk,Wv -> contiguous bf16 w3[3*ELW] AND x -> xb[ELX] (RNE).
// grid 3584 x 256: first 1536 blocks = weights, last 2048 = x (block-aligned:
// 1536*2048 == 3*ELW, so the branch is uniform per block).
__global__ __launch_bounds__(256) void convert4(const void* __restrict__ w0,
                                                const void* __restrict__ w1,
                                                const void* __restrict__ w2,
                                                const void* __restrict__ x,
                                                ushort* __restrict__ w3,
                                                ushort* __restrict__ xb,
                                                const int* __restrict__ flag) {
  const size_t i = ((size_t)blockIdx.x * 256 + threadIdx.x) * 8;
  const int isbf = *flag;
  if (i < 3u * ELW) {
    const int wi = (int)(i >> 20);
    const size_t off = i & (ELW - 1);
    const void* src = (wi == 0) ? w0 : (wi == 1) ? w1 : w2;
    if (isbf) *(short8*)(w3 + i) = *(const short8*)((const ushort*)src + off);
    else      *(short8*)(w3 + i) = cvt8_rne((const float*)src + off);
  } else {
    const size_t j = i - 3u * ELW;           // 0..ELX-1
    if (isbf) *(short8*)(xb + j) = *(const short8*)((const ushort*)x + j);
    else      *(short8*)(xb + j) = cvt8_rne((const float*)x + j);
  }
}

// convert Wo -> bf16 (runs after attn3; dst = q_ws, dead by then). grid 512.
__global__ __launch_bounds__(256) void convertW1(const void* __restrict__ wo,
                                                 ushort* __restrict__ dst,
                                                 const int* __restrict__ flag) {
  const size_t i = ((size_t)blockIdx.x * 256 + threadIdx.x) * 8;
  if (*flag) *(short8*)(dst + i) = *(const short8*)((const ushort*)wo + i);
  else       *(short8*)(dst + i) = cvt8_rne((const float*)wo + i);
}

// ---------------------------------------------------------------------------
// QKV GEMM, all-bf16 both-operand gll16, issue-early/drain-late:
//   tile 256m x 192n, BK=64, 8 waves (2x4), acc[8][3], 16 K-tiles,
//   ONE barrier per K-tile. XOR chunk swizzle (slot = chunk ^ (row&7)),
//   pre-swizzled gll SOURCE + swizzled read (both-sides, rule #21).
// Grid 256 = 1 block/CU. XCD k owns mt-pair {2k,2k+1}: xb slice L2-resident.
// ---------------------------------------------------------------------------
#define ASZ (256 * 64)   // elems per A buffer
#define BSZ (192 * 64)   // elems per B buffer

__device__ __forceinline__ void qkv_core(const ushort* __restrict__ xb,
                                         const ushort* __restrict__ W,
                                         int m0, int n0r,
                                         ushort* As0, ushort* Bs0,
                                         f32x4 acc[8][3]) {
  const int tid  = threadIdx.x;
  const int w    = tid >> 6;
  const int lane = tid & 63;
  const int quad = lane >> 4;
  const int l16  = lane & 15;
  const int wr   = w >> 2, wc = w & 3;

  const int prow = tid >> 3;                 // row within 64-row issue group
  const int c    = tid & 7;                  // physical 16B slot within row
  const int sw   = c ^ (prow & 7);           // logical chunk staged at slot c
  const int rsw  = l16 & 7;                  // read-side swizzle key

  auto stageB = [&](int cur, int kt) {
#pragma unroll
    for (int g = 0; g < 3; ++g)
      gll16(W + (size_t)(n0r + g * 64 + prow) * EMB + kt * 64 + sw * 8,
            Bs0 + cur * BSZ + g * 4096 + w * 512);
  };
  auto stageA = [&](int cur, int kt) {
#pragma unroll
    for (int g = 0; g < 4; ++g)
      gll16(xb + (size_t)(m0 + g * 64 + prow) * EMB + kt * 64 + sw * 8,
            As0 + cur * ASZ + g * 4096 + w * 512);
  };

  stageB(0, 0);
  stageA(0, 0);
  __syncthreads();

  for (int t = 0; t < 16; ++t) {
    const int cur = t & 1, nxt = cur ^ 1;
    if (t < 15) {                            // issue-early (cover the drain)
      stageB(nxt, t + 1);
      stageA(nxt, t + 1);
    }

    const ushort* Ab = As0 + cur * ASZ;
    const ushort* Bb = Bs0 + cur * BSZ;
    short8 bf_[3][2];
#pragma unroll
    for (int ni = 0; ni < 3; ++ni)
#pragma unroll
      for (int ks = 0; ks < 2; ++ks)
        bf_[ni][ks] = *(const short8*)&Bb[(wc * 48 + ni * 16 + l16) * 64 +
                                          ((ks * 4 + quad) ^ rsw) * 8];
#pragma unroll
    for (int mi = 0; mi < 8; ++mi) {
      const int arow = (wr * 128 + mi * 16 + l16) * 64;
      short8 a0 = *(const short8*)&Ab[arow + ((quad) ^ rsw) * 8];
      short8 a1 = *(const short8*)&Ab[arow + ((4 + quad) ^ rsw) * 8];
#pragma unroll
      for (int ni = 0; ni < 3; ++ni) {
        acc[mi][ni] = __builtin_amdgcn_mfma_f32_16x16x32_bf16(a0, bf_[ni][0], acc[mi][ni], 0, 0, 0);
        acc[mi][ni] = __builtin_amdgcn_mfma_f32_16x16x32_bf16(a1, bf_[ni][1], acc[mi][ni], 0, 0, 0);
      }
    }
    __syncthreads();                         // single drain point per K-tile
  }
}

__global__ __launch_bounds__(512, 2) void qkv_pipe(const ushort* __restrict__ xb,
                                                   const ushort* __restrict__ w3,
                                                   const void* __restrict__ bq,
                                                   const void* __restrict__ bk,
                                                   const void* __restrict__ bv,
                                                   ushort* __restrict__ qo,
                                                   ushort* __restrict__ ko,
                                                   ushort* __restrict__ vo,
                                                   const int* __restrict__ flag) {
  __shared__ __align__(16) ushort As2[2 * ASZ];   // 64 KB
  __shared__ __align__(16) ushort Bs2[2 * BSZ];   // 48 KB
  const int bid = blockIdx.x;              // 256 blocks, 1/CU
  const int xcd = bid & 7;                 // HW round-robin: bid%8 = XCD
  const int mt  = xcd * 2 + ((bid >> 3) & 1);  // XCD k owns mt {2k,2k+1}
  const int nt  = bid >> 4;                // 0..15: W panels stream through
  const int m0  = mt * 256;
  const int n0r = nt * 192;

  f32x4 acc[8][3];
#pragma unroll
  for (int a = 0; a < 8; ++a)
#pragma unroll
    for (int b = 0; b < 3; ++b) acc[a][b] = (f32x4){0.f, 0.f, 0.f, 0.f};

  qkv_core(xb, w3, m0, n0r, As2, Bs2, acc);

  const int isbf = *flag;
  const int tid  = threadIdx.x;
  const int w    = tid >> 6;
  const int lane = tid & 63;
  const int quad = lane >> 4;
  const int l16  = lane & 15;
  const int wr   = w >> 2, wc = w & 3;

#pragma unroll
  for (int ni = 0; ni < 3; ++ni) {
    const int n   = n0r + wc * 48 + ni * 16 + l16;   // 0..3071
    const int mat = n >> 10, nn = n & 1023;          // uniform per fragment
    const void* bias = (mat == 0) ? bq : (mat == 1) ? bk : bv;
    const float bv_ = isbf ? bf2f(((const ushort*)bias)[nn]) : ((const float*)bias)[nn];
    const int h = nn >> 6, d = nn & 63;
    const float sc = (mat == 0) ? CSCALE : 1.0f;
    ushort* dqk = (mat == 0) ? qo : ko;
#pragma unroll
    for (int mi = 0; mi < 8; ++mi) {
      const int m = m0 + wr * 128 + mi * 16 + quad * 4;
      const int b = m >> 11, tt = m & (TT - 1);
      if (mat == 2) {
        us4 pk;
#pragma unroll
        for (int r = 0; r < 4; ++r) pk[r] = f2bf(acc[mi][ni][r] + bv_);
        *(us4*)&vo[((size_t)((b * HEADS + h) * HD + d)) * TT + tt] = pk;
      } else {
#pragma unroll
        for (int r = 0; r < 4; ++r)
          dqk[((size_t)((b * HEADS + h) * TT + tt + r)) * HD + d] =
              f2bf((acc[mi][ni][r] + bv_) * sc);
      }
    }
  }
}

// ---------------------------------------------------------------------------
// Causal flash attention with S^T trick (QK MFMA computes S^T: A=K, B=Q).
// r10: reverted to the r8 structure (57.6 µs verified). r9's gll K/V
// double-buffer regressed (64.1 µs): compiler can't disambiguate gll LDS
// writes vs compute's ds_reads -> serializes stage->vmcnt->compute.
// [rows][64] linear + XOR chunk swizzle (slot = chunk ^ (row&7));
// reg-staged writes -> swizzle on LDS dest + read.
// ---------------------------------------------------------------------------
__global__ __launch_bounds__(256) void attn3(const ushort* __restrict__ qw,
                                             const ushort* __restrict__ kw,
                                             const ushort* __restrict__ vtw,
                                             ushort* __restrict__ out) {
  __shared__ __align__(16) ushort Ks[64 * 64];      // 8 KB
  __shared__ __align__(16) ushort Vts[64 * 64];     // 8 KB
  __shared__ __align__(16) ushort Ps[4][16 * 64];   // 8 KB (2 KB/wave)

  const int bid = blockIdx.x;
  const int j  = bid >> 8;
  const int r8 = bid & 255;
  const int qh = r8 & 31;
  const int bh = j * 8 + (r8 >> 5);
  int qt;
  if      (j == 0) qt = qh;
  else if (j == 1) qt = 31 - qh;
  else if (j == 2) qt = (qh + 16) & 31;
  else             qt = 31 - ((qh + 16) & 31);
  const int h = bh & (HEADS - 1);
  const int b = bh >> 4;

  const int tid  = threadIdx.x;
  const int w    = tid >> 6;
  const int lane = tid & 63;
  const int quad = lane >> 4;
  const int l16  = lane & 15;
  const int rsw  = l16 & 7;          // read-side swizzle key (fragment row&7)

  const size_t hoff = ((size_t)(b * HEADS + h)) * TT * HD;
  const ushort* Qg = qw + hoff;
  const ushort* Kg = kw + hoff;
  const ushort* Vg = vtw + hoff;     // [d][T]
  const int q0 = qt * 64;

  short8 qf[2];
  {
    const ushort* qrow = Qg + (size_t)(q0 + w * 16 + l16) * HD;
    qf[0] = *(const short8*)(qrow + quad * 8);
    qf[1] = *(const short8*)(qrow + 32 + quad * 8);
  }

  const int row = tid >> 2;          // 0..63 staging row
  const int cq  = (tid & 3) * 2;     // logical chunk pair within the row
  const int s0  = (cq)     ^ (row & 7);   // swizzled dest slots
  const int s1  = (cq + 1) ^ (row & 7);
  const int c0  = cq * 8;            // ushort col of first chunk (global src)
  const ushort* Kbase = Kg + (size_t)row * HD + c0;   // + kt*64*HD
  const ushort* Vbase = Vg + (size_t)row * TT + c0;   // + kt*64

  float lsp[4] = {0.f, 0.f, 0.f, 0.f};   // per-lane partial row sums, q = l16
  f32x4 O[4];
#pragma unroll
  for (int ni = 0; ni < 4; ++ni) O[ni] = (f32x4){0.f, 0.f, 0.f, 0.f};

  auto compute_tile = [&](int kt) {
    // S^T = K . Q^T : lane(quad,l16) holds keys ni*16+quad*4+r at q-col l16
    f32x4 s[4];
#pragma unroll
    for (int ni = 0; ni < 4; ++ni) s[ni] = (f32x4){0.f, 0.f, 0.f, 0.f};
#pragma unroll
    for (int ks = 0; ks < 2; ++ks) {
#pragma unroll
      for (int ni = 0; ni < 4; ++ni) {
        short8 kb = *(const short8*)&Ks[(ni * 16 + l16) * 64 +
                                        ((ks * 4 + quad) ^ rsw) * 8];
        s[ni] = __builtin_amdgcn_mfma_f32_16x16x32_bf16(kb, qf[ks], s[ni], 0, 0, 0);
      }
    }
    if (kt == qt) {   // diagonal tile: mask key > q (both local to the tile)
      const int qq = w * 16 + l16;
#pragma unroll
      for (int ni = 0; ni < 4; ++ni) {
#pragma unroll
        for (int r = 0; r < 4; ++r)
          if (ni * 16 + quad * 4 + r > qq) s[ni][r] = -__builtin_inff();
      }
    }
    // p = 2^s; keys are register-contiguous -> pack pairs + b64 writes.
#pragma unroll
    for (int ni = 0; ni < 4; ++ni) {
      union { float f; uint32_t u; } p0, p1, p2, p3;
      p0.f = exp2f(s[ni][0]); p1.f = exp2f(s[ni][1]);
      p2.f = exp2f(s[ni][2]); p3.f = exp2f(s[ni][3]);
      lsp[ni] += (p0.f + p1.f) + (p2.f + p3.f);
      uint2 dw;
      dw.x = pack2(p0.u, p1.u);
      dw.y = pack2(p2.u, p3.u);
      const int slot = (2 * ni + (quad >> 1)) ^ rsw;
      *(uint2*)&Ps[w][l16 * 64 + slot * 8 + (quad & 1) * 4] = dw;
    }
    // O += P V  (A = P from wave-private LDS, B = Vt)
#pragma unroll
    for (int ks = 0; ks < 2; ++ks) {
      short8 a = *(const short8*)&Ps[w][l16 * 64 + ((ks * 4 + quad) ^ rsw) * 8];
#pragma unroll
      for (int ni = 0; ni < 4; ++ni) {
        short8 vb = *(const short8*)&Vts[(ni * 16 + l16) * 64 +
                                         ((ks * 4 + quad) ^ rsw) * 8];
        O[ni] = __builtin_amdgcn_mfma_f32_16x16x32_bf16(a, vb, O[ni], 0, 0, 0);
      }
    }
  };

  // named 2-set prefetch (no dynamic register indexing)
  short8 ak0, ak1, av0, av1;
  short8 bk0, bk1, bv0, bv1;
  ak0 = *(const short8*)(Kbase);
  ak1 = *(const short8*)(Kbase + 8);
  av0 = *(const short8*)(Vbase);
  av1 = *(const short8*)(Vbase + 8);

  for (int kt = 0; kt <= qt; ) {
    __syncthreads();
    *(short8*)&Ks[row * 64 + s0 * 8]  = ak0;
    *(short8*)&Ks[row * 64 + s1 * 8]  = ak1;
    *(short8*)&Vts[row * 64 + s0 * 8] = av0;
    *(short8*)&Vts[row * 64 + s1 * 8] = av1;
    if (kt + 1 <= qt) {
      const size_t ko_ = (size_t)(kt + 1) * 64 * HD;
      bk0 = *(const short8*)(Kbase + ko_);
      bk1 = *(const short8*)(Kbase + ko_ + 8);
      bv0 = *(const short8*)(Vbase + (kt + 1) * 64);
      bv1 = *(const short8*)(Vbase + (kt + 1) * 64 + 8);
    }
    __syncthreads();
    compute_tile(kt);
    ++kt;
    if (kt > qt) break;

    __syncthreads();
    *(short8*)&Ks[row * 64 + s0 * 8]  = bk0;
    *(short8*)&Ks[row * 64 + s1 * 8]  = bk1;
    *(short8*)&Vts[row * 64 + s0 * 8] = bv0;
    *(short8*)&Vts[row * 64 + s1 * 8] = bv1;
    if (kt + 1 <= qt) {
      const size_t ko_ = (size_t)(kt + 1) * 64 * HD;
      ak0 = *(const short8*)(Kbase + ko_);
      ak1 = *(const short8*)(Kbase + ko_ + 8);
      av0 = *(const short8*)(Vbase + (kt + 1) * 64);
      av1 = *(const short8*)(Vbase + (kt + 1) * 64 + 8);
    }
    __syncthreads();
    compute_tile(kt);
    ++kt;
  }

  // reduce ls across quads (each lane then holds total for q = l16)
  float lst = (lsp[0] + lsp[1]) + (lsp[2] + lsp[3]);
  lst += __shfl_xor(lst, 16);
  lst += __shfl_xor(lst, 32);

#pragma unroll
  for (int r = 0; r < 4; ++r) {
    const float inv = 1.0f / __shfl(lst, (lane & 48) | (quad * 4 + r));
    const int t = q0 + w * 16 + quad * 4 + r;
#pragma unroll
    for (int ni = 0; ni < 4; ++ni) {
      out[((size_t)(b * TT + t)) * EMB + h * HD + ni * 16 + l16] = f2bf(O[ni][r] * inv);
    }
  }
}

// ---------------------------------------------------------------------------
// Output projection, r10: qkv_core template ported. Tile 128m x 128n, BK=64,
// 512 threads / 8 waves (2x4), acc[4][2], both operands bf16 via gll16 with
// the proven XOR chunk swizzle (pre-swizzled source + swizzled read).
// Grid 256 = 1 block/CU; XCD k owns mt {4k..4k+3} (A slice 1 MB L2-resident,
// Wo_bf16 2 MB L2-cacheable). One barrier per K-tile, issue-early staging.
// ---------------------------------------------------------------------------
#define PASZ (128 * 64)

__global__ __launch_bounds__(512, 2) void proj_pipe(const ushort* __restrict__ A,
                                                    const ushort* __restrict__ Wb,
                                                    const void* __restrict__ bo,
                                                    void* __restrict__ out,
                                                    const int* __restrict__ flag) {
  __shared__ __align__(16) ushort As2[2 * PASZ];   // 32 KB
  __shared__ __align__(16) ushort Bs2[2 * PASZ];   // 32 KB
  const int bid = blockIdx.x;              // 256 blocks, 1/CU
  const int xcd = bid & 7;
  const int mt  = xcd * 4 + ((bid >> 3) & 3);  // XCD k owns mt {4k..4k+3}
  const int nt  = bid >> 5;                // 0..7
  const int m0  = mt * 128;
  const int n0  = nt * 128;

  const int tid  = threadIdx.x;
  const int w    = tid >> 6;
  const int lane = tid & 63;
  const int quad = lane >> 4;
  const int l16  = lane & 15;
  const int wr   = w >> 2, wc = w & 3;

  const int prow = tid >> 3;               // 0..63 (issue-group row)
  const int sw   = (tid & 7) ^ (prow & 7); // pre-swizzled source chunk
  const int rsw  = l16 & 7;                // read-side swizzle key

  f32x4 acc[4][2];
#pragma unroll
  for (int i = 0; i < 4; ++i)
#pragma unroll
    for (int jj = 0; jj < 2; ++jj) acc[i][jj] = (f32x4){0.f, 0.f, 0.f, 0.f};

  auto stageA = [&](int cur, int kt) {
#pragma unroll
    for (int g = 0; g < 2; ++g)
      gll16(A + (size_t)(m0 + g * 64 + prow) * EMB + kt * 64 + sw * 8,
            As2 + cur * PASZ + g * 4096 + w * 512);
  };
  auto stageB = [&](int cur, int kt) {
#pragma unroll
    for (int g = 0; g < 2; ++g)
      gll16(Wb + (size_t)(n0 + g * 64 + prow) * EMB + kt * 64 + sw * 8,
            Bs2 + cur * PASZ + g * 4096 + w * 512);
  };

  stageA(0, 0);
  stageB(0, 0);
  __syncthreads();

  for (int t = 0; t < 16; ++t) {
    const int cur = t & 1, nxt = cur ^ 1;
    if (t < 15) {
      stageA(nxt, t + 1);
      stageB(nxt, t + 1);
    }
    const ushort* Ab = As2 + cur * PASZ;
    const ushort* Bb = Bs2 + cur * PASZ;
    short8 bf_[2][2];
#pragma unroll
    for (int ni = 0; ni < 2; ++ni)
#pragma unroll
      for (int ks = 0; ks < 2; ++ks)
        bf_[ni][ks] = *(const short8*)&Bb[(wc * 32 + ni * 16 + l16) * 64 +
                                          ((ks * 4 + quad) ^ rsw) * 8];
#pragma unroll
    for (int mi = 0; mi < 4; ++mi) {
      const int arow = (wr * 64 + mi * 16 + l16) * 64;
      short8 a0 = *(const short8*)&Ab[arow + ((quad) ^ rsw) * 8];
      short8 a1 = *(const short8*)&Ab[arow + ((4 + quad) ^ rsw) * 8];
#pragma unroll
      for (int ni = 0; ni < 2; ++ni) {
        acc[mi][ni] = __builtin_amdgcn_mfma_f32_16x16x32_bf16(a0, bf_[ni][0], acc[mi][ni], 0, 0, 0);
        acc[mi][ni] = __builtin_amdgcn_mfma_f32_16x16x32_bf16(a1, bf_[ni][1], acc[mi][ni], 0, 0, 0);
      }
    }
    __syncthreads();
  }

  const int isbf = *flag;
#pragma unroll
  for (int ni = 0; ni < 2; ++ni) {
    const int n = n0 + wc * 32 + ni * 16 + l16;
    const float bv_ = isbf ? bf2f(((const ushort*)bo)[n]) : ((const float*)bo)[n];
#pragma unroll
    for (int mi = 0; mi < 4; ++mi) {
#pragma unroll
      for (int r = 0; r < 4; ++r) {
        const int m = m0 + wr * 64 + mi * 16 + quad * 4 + r;
        const float v = acc[mi][ni][r] + bv_;
        if (isbf) ((ushort*)out)[(size_t)m * EMB + n] = f2bf(v);
        else      ((float*) out)[(size_t)m * EMB + n] = v;
      }
    }
  }
}

// ---------------------------------------------------------------------------
extern "C" void kernel_launch(void* const* d_in, const int* in_sizes, int n_in,
                              void* d_out, int out_size, void* d_ws, size_t ws_size,
                              hipStream_t stream) {
  const void* x  = d_in[0];
  const void* Wq = d_in[1];
  const void* bq = d_in[2];
  const void* Wk = d_in[3];
  const void* bk = d_in[4];
  const void* Wv = d_in[5];
  const void* bv = d_in[6];
  const void* Wo = d_in[7];
  const void* bo = d_in[8];

  int* flag = (int*)d_ws;
  ushort* base = (ushort*)((char*)d_ws + 256);

  // ws layout (33.56 MB budget):
  //   q:[0,ELX) k:[ELX,2ELX) vt:[2ELX,3ELX)
  //   w3 (3*ELW, dead after qkv) and o (ELX) share [3ELX,4ELX)
  // xb (bf16 copy of x, ELX ushorts) lives in d_out: dead before proj_pipe
  // writes it. Wo_bf16 (ELW ushorts) lives in q_ws: written by convertW1
  // AFTER attn3 (q dead by then), read by proj_pipe.
  ushort* q_ws  = base;
  ushort* k_ws  = q_ws + ELX;
  ushort* vt_ws = k_ws + ELX;
  ushort* w3    = vt_ws + ELX;
  ushort* o_ws  = vt_ws + ELX;
  ushort* xb    = (ushort*)d_out;
  ushort* wo_b  = q_ws;

  detect_dtype<<<dim3(1), dim3(64), 0, stream>>>((const uint32_t*)x, flag);
  convert4<<<dim3(3584), dim3(256), 0, stream>>>(Wq, Wk, Wv, x, w3, xb, flag);
  qkv_pipe<<<dim3(256), dim3(512), 0, stream>>>(xb, w3, bq, bk, bv,
                                                q_ws, k_ws, vt_ws, flag);
  attn3<<<dim3(1024), dim3(256), 0, stream>>>(q_ws, k_ws, vt_ws, o_ws);
  convertW1<<<dim3(512), dim3(256), 0, stream>>>(Wo, wo_b, flag);
  proj_pipe<<<dim3(256), dim3(512), 0, stream>>>(o_ws, wo_b, bo, d_out, flag);
}